// Round 1
// 17679.320 us; speedup vs baseline: 1.1377x; 1.1377x over previous
//
#include <hip/hip_runtime.h>
#include <math.h>

// ---------------------------------------------------------------------------
// FullModelTest: 4 stacked LSTMs (H=48,96,144,48) + 3 FF blocks, T=200, B=4096.
// Round 3: occupancy fix. MROWS 16->8 => grid 512 = 2 blocks/CU (was 1), so
// barrier/L2-latency stalls of one block overlap the other block's compute.
// L3 now single 8-row pass; f1a fused with L1-mm and f1b with L1-epi on
// disjoint thread sets; post-emit barrier removed. 13 barriers/step (was 16).
// Weight rows streamed from L2 as float4; x^T broadcast-read from LDS.
// ---------------------------------------------------------------------------

#define NT 256
#define MROWS 8
#define TSTEPS 200
#define BATCH 4096
#define XS 10      // x^T row stride (floats), even (float2-aligned), 8 rows used
#define GS 9       // gate buffer stride (8 rows used)

// ---- workspace float offsets (weights in [c][k] concat layout) ----
#define L1W   0
#define L1B   18432
#define L2W   18624
#define L2B   92352
#define L3W   92736
#define L3B   258624
#define L4W   259200
#define L4B   277632
#define F1AW  277824
#define F1AB  278208
#define F1BW  278256
#define F1BB  280560
#define F2AW  280608
#define F2AB  301344
#define F2BW  301488
#define F2BB  315312
#define F3AW  315408
#define F3AB  324624
#define F3BW  324720
#define F3BB  329328
// total 329376 floats = 1.32 MB

// ---- pool float offsets ----
#define P_GB   0     // L1/L2/L3 gate buffers (max 576*9 = 5184)
#define P_SAT  5184  // sa input, 8x10 = 80 (ends 5264)
#define P_F1H  5264  // f1 hidden, 48x10 = 480 (ends 5744)
#define P_F2H  0     // 144x10 = 1440
#define P_O4T  1440  // 96x10 = 960 (ends 2400)
#define P_F3H  2400  // 96x10 = 960 (ends 3360)
#define P_OUT5 3360  // 48x10 = 480 (ends 3840)
#define P_L4G  0     // 192x9 = 1728
#define POOLSZ 5744

__device__ __forceinline__ float sigf(float x) { return 1.0f / (1.0f + __expf(-x)); }

// ---------------------------------------------------------------------------
// Prep kernels: weights to [c][k] (ih|hh concat for LSTM, zero-padded K for FF)
// ---------------------------------------------------------------------------
__global__ void prep_lstm(const float* __restrict__ wih, const float* __restrict__ whh,
                          const float* __restrict__ bih, const float* __restrict__ bhh,
                          float* __restrict__ W, float* __restrict__ bias,
                          int Din, int H) {
    int K = Din + H;
    int N = 4 * H;
    int total = N * K;
    for (int idx = blockIdx.x * blockDim.x + threadIdx.x; idx < total + N;
         idx += gridDim.x * blockDim.x) {
        if (idx < total) {
            int c = idx / K;
            int k = idx - c * K;
            W[idx] = (k < Din) ? wih[c * Din + k] : whh[c * H + (k - Din)];
        } else {
            int c = idx - total;
            bias[c] = bih[c] + bhh[c];
        }
    }
}

__global__ void prep_ff(const float* __restrict__ w, const float* __restrict__ b,
                        float* __restrict__ W, float* __restrict__ bias,
                        int K, int Kpad, int N) {
    int total = N * Kpad;
    for (int idx = blockIdx.x * blockDim.x + threadIdx.x; idx < total + N;
         idx += gridDim.x * blockDim.x) {
        if (idx < total) {
            int c = idx / Kpad;
            int k = idx - c * Kpad;
            W[idx] = (k < K) ? w[c * K + k] : 0.0f;
        } else {
            int c = idx - total;
            bias[c] = b[c];
        }
    }
}

// ---------------------------------------------------------------------------
// Column matmul: TC columns per thread, ROWS rows. Weight rows streamed from
// global (float4, L2-resident); x^T from LDS (wave-uniform float2 broadcast).
// Result (+bias, opt relu) written to g*[r].
// ---------------------------------------------------------------------------
template <int TC, int ROWS, bool RELU>
__device__ __forceinline__ void mm(
    const float* __restrict__ w0, const float* __restrict__ w1,
    const float* __restrict__ w2,
    float b0, float b1, float b2,
    const float* __restrict__ x0, int K0,
    const float* __restrict__ x1, int K1,
    const float* __restrict__ x2, int K2,
    int rbase,
    float* __restrict__ g0, float* __restrict__ g1, float* __restrict__ g2) {
    float a0[ROWS], a1[ROWS], a2[ROWS];
#pragma unroll
    for (int r = 0; r < ROWS; ++r) { a0[r] = 0.f; a1[r] = 0.f; a2[r] = 0.f; }
    int ko = 0;
#pragma unroll
    for (int s = 0; s < 3; ++s) {
        const float* xb = (s == 0) ? x0 : (s == 1) ? x1 : x2;
        int K = (s == 0) ? K0 : (s == 1) ? K1 : K2;
        if (K > 0) {
            const float* xp = xb + rbase;
#pragma unroll 2
            for (int k = 0; k < K; k += 4) {
                float4 wv0 = *(const float4*)(w0 + ko + k);
                float4 wv1 = (TC > 1) ? *(const float4*)(w1 + ko + k) : wv0;
                float4 wv2 = (TC > 2) ? *(const float4*)(w2 + ko + k) : wv0;
                const float* f0 = (const float*)&wv0;
                const float* f1p = (const float*)&wv1;
                const float* f2p = (const float*)&wv2;
#pragma unroll
                for (int q = 0; q < 4; ++q) {
                    const float* xq = xp + (k + q) * XS;
#pragma unroll
                    for (int rr = 0; rr < ROWS; rr += 2) {
                        float2 xv = *(const float2*)(xq + rr);
                        a0[rr]     = fmaf(xv.x, f0[q], a0[rr]);
                        a0[rr + 1] = fmaf(xv.y, f0[q], a0[rr + 1]);
                        if (TC > 1) {
                            a1[rr]     = fmaf(xv.x, f1p[q], a1[rr]);
                            a1[rr + 1] = fmaf(xv.y, f1p[q], a1[rr + 1]);
                        }
                        if (TC > 2) {
                            a2[rr]     = fmaf(xv.x, f2p[q], a2[rr]);
                            a2[rr + 1] = fmaf(xv.y, f2p[q], a2[rr + 1]);
                        }
                    }
                }
            }
            ko += K;
        }
    }
#pragma unroll
    for (int r = 0; r < ROWS; ++r) {
        float v0 = a0[r] + b0;
        if (RELU) v0 = fmaxf(v0, 0.f);
        g0[r] = v0;
        if (TC > 1) {
            float v1 = a1[r] + b1;
            if (RELU) v1 = fmaxf(v1, 0.f);
            g1[r] = v1;
        }
        if (TC > 2) {
            float v2 = a2[r] + b2;
            if (RELU) v2 = fmaxf(v2, 0.f);
            g2[r] = v2;
        }
    }
}

// ---------------------------------------------------------------------------
// LSTM epilogue: combine i/f/g/o from gate buffer; c-state in regs, fixed
// ownership idx = idx0 + n*stride; write h into x^T slot.
// ---------------------------------------------------------------------------
template <int H, int R, int NCS>
__device__ __forceinline__ void lstm_epi(const float* __restrict__ gb, int gs,
                                         float* __restrict__ hT,
                                         float (&cs)[NCS], int idx0, int stride) {
    const int E = H * R;
#pragma unroll
    for (int n = 0; n < NCS; ++n) {
        int idx = idx0 + n * stride;
        if (idx < E) {
            int r = idx & (R - 1);
            int j = idx / R;
            float gi = gb[j * gs + r];
            float gf = gb[(j + H) * gs + r];
            float gg = gb[(j + 2 * H) * gs + r];
            float go = gb[(j + 3 * H) * gs + r];
            float c2 = sigf(gf) * cs[n] + sigf(gi) * tanhf(gg);
            cs[n] = c2;
            hT[j * XS + r] = sigf(go) * tanhf(c2);
        }
    }
}

template <int H, int R, int NCS>
__device__ __forceinline__ void c_init(const float* __restrict__ c0, int r0,
                                       float (&cs)[NCS], int idx0, int stride) {
    const int E = H * R;
#pragma unroll
    for (int n = 0; n < NCS; ++n) {
        int idx = idx0 + n * stride;
        if (idx < E) {
            int r = idx & (R - 1);
            int j = idx / R;
            cs[n] = c0[(size_t)(r0 + r) * H + j];
        }
    }
}

// ---------------------------------------------------------------------------
__global__ __launch_bounds__(256, 2) void model_kernel(
    const float* __restrict__ tactiles, const float* __restrict__ actions,
    const float* __restrict__ context, const float* __restrict__ ws,
    const float* __restrict__ h01, const float* __restrict__ c01,
    const float* __restrict__ h02, const float* __restrict__ c02,
    const float* __restrict__ h03, const float* __restrict__ c03,
    const float* __restrict__ h04, const float* __restrict__ c04,
    float* __restrict__ out) {
    __shared__ __align__(16) float tacT[48 * XS];
    __shared__ __align__(16) float ctxT[48 * XS];
    __shared__ __align__(16) float h1T[48 * XS];
    __shared__ __align__(16) float h2T[96 * XS];
    __shared__ __align__(16) float h3T[144 * XS];
    __shared__ __align__(16) float h4T[48 * XS];
    __shared__ __align__(16) float saoT[48 * XS];
    __shared__ __align__(16) float pool[POOLSZ];

    const int tid = threadIdx.x;
    const int r0 = blockIdx.x * MROWS;

    // ---- init h states into x^T slots ----
    for (int i = tid; i < 48 * 8; i += NT) {
        int r = i & 7, j = i >> 3;
        h1T[j * XS + r] = h01[(size_t)(r0 + r) * 48 + j];
        h4T[j * XS + r] = h04[(size_t)(r0 + r) * 48 + j];
    }
    for (int i = tid; i < 96 * 8; i += NT) {
        int r = i & 7, j = i >> 3;
        h2T[j * XS + r] = h02[(size_t)(r0 + r) * 96 + j];
    }
    for (int i = tid; i < 144 * 8; i += NT) {
        int r = i & 7, j = i >> 3;
        h3T[j * XS + r] = h03[(size_t)(r0 + r) * 144 + j];
    }

    // ---- c states in registers ----
    float cs1[2] = {0.f, 0.f};
    float cs2[3] = {0.f, 0.f, 0.f};
    float cs3[5] = {0.f, 0.f, 0.f, 0.f, 0.f};
    float cs4[2] = {0.f, 0.f};
    // L1 epi runs on threads 64..255 (idx0 = tid-64, stride 192) so that
    // threads 0..47 can run f1b concurrently; ownership must match here.
    if (tid >= 64) c_init<48, 8, 2>(c01, r0, cs1, tid - 64, 192);
    c_init<96, 8, 3>(c02, r0, cs2, tid, NT);
    c_init<144, 8, 5>(c03, r0, cs3, tid, NT);
    c_init<48, 8, 2>(c04, r0, cs4, tid, NT);

    // ---- hoist biases into regs (constant across t) ----
    float bL1  = (tid < 192) ? ws[L1B + tid] : 0.f;
    float bL2a = ws[L2B + tid];
    float bL2b = (tid < 128) ? ws[L2B + tid + 256] : 0.f;
    float bL3a = ws[L3B + tid];
    float bL3b = ws[L3B + tid + 256];
    float bL3c = (tid < 64) ? ws[L3B + tid + 512] : 0.f;
    float bL4  = (tid < 192) ? ws[L4B + tid] : 0.f;
    float bF1a = (tid >= 192 && tid < 240) ? ws[F1AB + (tid - 192)] : 0.f;
    float bF1b = (tid < 48) ? ws[F1BB + tid] : 0.f;
    float bF2a = (tid < 144) ? ws[F2AB + tid] : 0.f;
    float bF2b = (tid < 192) ? ws[F2BB + (tid % 96)] : 0.f;
    float bF3a = (tid < 192) ? ws[F3AB + (tid % 96)] : 0.f;
    float bF3b = (tid < 192) ? ws[F3BB + (tid % 48)] : 0.f;

    const int wvid = tid >> 6;
    __syncthreads();

    for (int t = 0; t < TSTEPS; ++t) {
        // ---- stage: tactile (t<6), context, sa (runs concurrent with emit of t-1) ----
        if (t < 6) {
            const float* src = tactiles + (size_t)t * BATCH * 48 + (size_t)r0 * 48;
            for (int i = tid; i < 96; i += NT) {
                int r = i / 12, k4 = (i % 12) * 4;
                float4 v = *(const float4*)(src + r * 48 + k4);
                tacT[(k4 + 0) * XS + r] = v.x;
                tacT[(k4 + 1) * XS + r] = v.y;
                tacT[(k4 + 2) * XS + r] = v.z;
                tacT[(k4 + 3) * XS + r] = v.w;
            }
        }
        {
            const float* src = context + (size_t)t * BATCH * 48 + (size_t)r0 * 48;
            for (int i = tid; i < 96; i += NT) {
                int r = i / 12, k4 = (i % 12) * 4;
                float4 v = *(const float4*)(src + r * 48 + k4);
                ctxT[(k4 + 0) * XS + r] = v.x;
                ctxT[(k4 + 1) * XS + r] = v.y;
                ctxT[(k4 + 2) * XS + r] = v.z;
                ctxT[(k4 + 3) * XS + r] = v.w;
            }
        }
        if (tid < 64) {  // sa = [state=actions[0] | actions[t]] K-rows 0..5, pad 6..7
            int r = tid & 7, k = tid >> 3;
            float v = 0.f;
            if (k < 3) v = actions[(size_t)(r0 + r) * 3 + k];
            else if (k < 6) v = actions[(size_t)t * BATCH * 3 + (size_t)(r0 + r) * 3 + (k - 3)];
            pool[P_SAT + k * XS + r] = v;
        }
        __syncthreads();

        // ---- L1 mm (threads 0-191) ∥ f1a 6(pad8)->48 relu (threads 192-239) ----
        {
            const float* x1 = (t < 6) ? tacT : h4T;
            if (tid < 192)
                mm<1, 8, false>(ws + L1W + tid * 96, ws, ws, bL1, 0.f, 0.f,
                                x1, 48, h1T, 48, nullptr, 0, 0,
                                pool + P_GB + tid * GS, nullptr, nullptr);
            else if (tid < 240)
                mm<1, 8, true>(ws + F1AW + (tid - 192) * 8, ws, ws, bF1a, 0.f, 0.f,
                               pool + P_SAT, 8, nullptr, 0, nullptr, 0, 0,
                               pool + P_F1H + (tid - 192) * XS, nullptr, nullptr);
        }
        __syncthreads();

        // ---- f1b 48->48 relu -> saoT (threads 0-47) ∥ L1 epi (threads 64-255) ----
        if (tid < 48)
            mm<1, 8, true>(ws + F1BW + tid * 48, ws, ws, bF1b, 0.f, 0.f,
                           pool + P_F1H, 48, nullptr, 0, nullptr, 0, 0,
                           saoT + tid * XS, nullptr, nullptr);
        else if (tid >= 64)
            lstm_epi<48, 8, 2>(pool + P_GB, GS, h1T, cs1, tid - 64, 192);
        __syncthreads();

        // ---- L2: x=[ctx|h1|h2] ----
        if (wvid < 2)
            mm<2, 8, false>(ws + L2W + (size_t)tid * 192, ws + L2W + (size_t)(tid + 256) * 192,
                            ws, bL2a, bL2b, 0.f,
                            ctxT, 48, h1T, 48, h2T, 96, 0,
                            pool + P_GB + tid * GS, pool + P_GB + (tid + 256) * GS, nullptr);
        else
            mm<1, 8, false>(ws + L2W + (size_t)tid * 192, ws, ws, bL2a, 0.f, 0.f,
                            ctxT, 48, h1T, 48, h2T, 96, 0,
                            pool + P_GB + tid * GS, nullptr, nullptr);
        __syncthreads();
        lstm_epi<96, 8, 3>(pool + P_GB, GS, h2T, cs2, tid, NT);
        __syncthreads();

        // ---- L3: x=[sa_out|h2|h3], single 8-row pass ----
        if (wvid == 0)
            mm<3, 8, false>(ws + L3W + (size_t)tid * 288, ws + L3W + (size_t)(tid + 256) * 288,
                            ws + L3W + (size_t)(tid + 512) * 288, bL3a, bL3b, bL3c,
                            saoT, 48, h2T, 96, h3T, 144, 0,
                            pool + P_GB + tid * GS, pool + P_GB + (tid + 256) * GS,
                            pool + P_GB + (tid + 512) * GS);
        else
            mm<2, 8, false>(ws + L3W + (size_t)tid * 288, ws + L3W + (size_t)(tid + 256) * 288,
                            ws, bL3a, bL3b, 0.f,
                            saoT, 48, h2T, 96, h3T, 144, 0,
                            pool + P_GB + tid * GS, pool + P_GB + (tid + 256) * GS, nullptr);
        __syncthreads();
        lstm_epi<144, 8, 5>(pool + P_GB, GS, h3T, cs3, tid, NT);
        __syncthreads();

        // ---- f2a: 144 -> 144, relu ----
        if (tid < 144)
            mm<1, 8, true>(ws + F2AW + tid * 144, ws, ws, bF2a, 0.f, 0.f,
                           h3T, 144, nullptr, 0, nullptr, 0, 0,
                           pool + P_F2H + tid * XS, nullptr, nullptr);
        __syncthreads();
        // ---- f2b: 144 -> 96, relu (4-row halves) ----
        if (tid < 192) {
            int c = tid % 96, rb = (tid / 96) * 4;
            mm<1, 4, true>(ws + F2BW + c * 144, ws, ws, bF2b, 0.f, 0.f,
                           pool + P_F2H, 144, nullptr, 0, nullptr, 0, rb,
                           pool + P_O4T + c * XS + rb, nullptr, nullptr);
        }
        __syncthreads();
        // ---- f3a: 96 -> 96, relu (4-row halves) ----
        if (tid < 192) {
            int c = tid % 96, rb = (tid / 96) * 4;
            mm<1, 4, true>(ws + F3AW + c * 96, ws, ws, bF3a, 0.f, 0.f,
                           pool + P_O4T, 96, nullptr, 0, nullptr, 0, rb,
                           pool + P_F3H + c * XS + rb, nullptr, nullptr);
        }
        __syncthreads();
        // ---- f3b: 96 -> 48, relu (2-row quarters) -> out5 ----
        if (tid < 192) {
            int c = tid % 48, rb = (tid / 48) * 2;
            mm<1, 2, true>(ws + F3BW + c * 96, ws, ws, bF3b, 0.f, 0.f,
                           pool + P_F3H, 96, nullptr, 0, nullptr, 0, rb,
                           pool + P_OUT5 + c * XS + rb, nullptr, nullptr);
        }
        __syncthreads();

        // ---- L4: x=[out5|h4] ----
        if (tid < 192)
            mm<1, 8, false>(ws + L4W + tid * 96, ws, ws, bL4, 0.f, 0.f,
                            pool + P_OUT5, 48, h4T, 48, nullptr, 0, 0,
                            pool + P_L4G + tid * GS, nullptr, nullptr);
        __syncthreads();
        lstm_epi<48, 8, 2>(pool + P_L4G, GS, h4T, cs4, tid, NT);
        __syncthreads();

        // ---- emit h4 (no trailing barrier: next stage phase touches only
        //      tacT/ctxT/P_SAT, disjoint from h4T; stage barrier orders L1) ----
        {
            float* dst = out + (size_t)t * BATCH * 48 + (size_t)r0 * 48;
            for (int i = tid; i < 96; i += NT) {
                int r = i / 12, j4 = (i % 12) * 4;
                float4 v;
                v.x = h4T[(j4 + 0) * XS + r];
                v.y = h4T[(j4 + 1) * XS + r];
                v.z = h4T[(j4 + 2) * XS + r];
                v.w = h4T[(j4 + 3) * XS + r];
                *(float4*)(dst + r * 48 + j4) = v;
            }
        }
    }
}

// ---------------------------------------------------------------------------
extern "C" void kernel_launch(void* const* d_in, const int* in_sizes, int n_in,
                              void* d_out, int out_size, void* d_ws, size_t ws_size,
                              hipStream_t stream) {
    const float* tac = (const float*)d_in[0];
    const float* act = (const float*)d_in[1];
    const float* ctx = (const float*)d_in[2];

    const float* l1_wih = (const float*)d_in[3];
    const float* l1_whh = (const float*)d_in[4];
    const float* l1_bih = (const float*)d_in[5];
    const float* l1_bhh = (const float*)d_in[6];
    const float* l2_wih = (const float*)d_in[7];
    const float* l2_whh = (const float*)d_in[8];
    const float* l2_bih = (const float*)d_in[9];
    const float* l2_bhh = (const float*)d_in[10];
    const float* l3_wih = (const float*)d_in[11];
    const float* l3_whh = (const float*)d_in[12];
    const float* l3_bih = (const float*)d_in[13];
    const float* l3_bhh = (const float*)d_in[14];
    const float* l4_wih = (const float*)d_in[15];
    const float* l4_whh = (const float*)d_in[16];
    const float* l4_bih = (const float*)d_in[17];
    const float* l4_bhh = (const float*)d_in[18];

    const float* f1_w1 = (const float*)d_in[19];
    const float* f1_b1 = (const float*)d_in[20];
    const float* f1_w2 = (const float*)d_in[21];
    const float* f1_b2 = (const float*)d_in[22];
    const float* f2_w1 = (const float*)d_in[23];
    const float* f2_b1 = (const float*)d_in[24];
    const float* f2_w2 = (const float*)d_in[25];
    const float* f2_b2 = (const float*)d_in[26];
    const float* f3_w1 = (const float*)d_in[27];
    const float* f3_b1 = (const float*)d_in[28];
    const float* f3_w2 = (const float*)d_in[29];
    const float* f3_b2 = (const float*)d_in[30];

    const float* h01 = (const float*)d_in[31];
    const float* c01 = (const float*)d_in[32];
    const float* h02 = (const float*)d_in[33];
    const float* c02 = (const float*)d_in[34];
    const float* h03 = (const float*)d_in[35];
    const float* c03 = (const float*)d_in[36];
    const float* h04 = (const float*)d_in[37];
    const float* c04 = (const float*)d_in[38];

    float* ws = (float*)d_ws;
    float* out = (float*)d_out;

    dim3 blk(NT);
    hipLaunchKernelGGL(prep_lstm, dim3(96), blk, 0, stream,
                       l1_wih, l1_whh, l1_bih, l1_bhh, ws + L1W, ws + L1B, 48, 48);
    hipLaunchKernelGGL(prep_lstm, dim3(256), blk, 0, stream,
                       l2_wih, l2_whh, l2_bih, l2_bhh, ws + L2W, ws + L2B, 96, 96);
    hipLaunchKernelGGL(prep_lstm, dim3(256), blk, 0, stream,
                       l3_wih, l3_whh, l3_bih, l3_bhh, ws + L3W, ws + L3B, 144, 144);
    hipLaunchKernelGGL(prep_lstm, dim3(96), blk, 0, stream,
                       l4_wih, l4_whh, l4_bih, l4_bhh, ws + L4W, ws + L4B, 48, 48);

    hipLaunchKernelGGL(prep_ff, dim3(4), blk, 0, stream,
                       f1_w1, f1_b1, ws + F1AW, ws + F1AB, 6, 8, 48);
    hipLaunchKernelGGL(prep_ff, dim3(16), blk, 0, stream,
                       f1_w2, f1_b2, ws + F1BW, ws + F1BB, 48, 48, 48);
    hipLaunchKernelGGL(prep_ff, dim3(96), blk, 0, stream,
                       f2_w1, f2_b1, ws + F2AW, ws + F2AB, 144, 144, 144);
    hipLaunchKernelGGL(prep_ff, dim3(64), blk, 0, stream,
                       f2_w2, f2_b2, ws + F2BW, ws + F2BB, 144, 144, 96);
    hipLaunchKernelGGL(prep_ff, dim3(48), blk, 0, stream,
                       f3_w1, f3_b1, ws + F3AW, ws + F3AB, 96, 96, 96);
    hipLaunchKernelGGL(prep_ff, dim3(24), blk, 0, stream,
                       f3_w2, f3_b2, ws + F3BW, ws + F3BB, 96, 96, 48);

    hipLaunchKernelGGL(model_kernel, dim3(BATCH / MROWS), blk, 0, stream,
                       tac, act, ctx, ws,
                       h01, c01, h02, c02, h03, c03, h04, c04, out);
}

// Round 2
// 16776.718 us; speedup vs baseline: 1.1990x; 1.0538x over previous
//
#include <hip/hip_runtime.h>
#include <math.h>

// ---------------------------------------------------------------------------
// FullModelTest: 4 stacked LSTMs (H=48,96,144,48) + 3 FF blocks, T=200, B=4096.
// Round 4: DS-pipe attack. Gate-interleaved fused LSTMs (L1/L2/L4): weights
// repacked [cell][k][4 gates]; one float4 weight + one LDS read per k feeds
// 8-16 FMAs; epilogue in registers (no gate buffer / epi phase / barrier).
// h-states double-buffered. float4 x-reads (XS=12) for L3/FFs. f1b fused with
// L2; staging(t+1) + emit fused with L4. 9 barriers/step (was 13).
// ---------------------------------------------------------------------------

#define NT 256
#define MROWS 8
#define TSTEPS 200
#define BATCH 4096
#define XS 12      // x^T row stride (floats), float4-aligned
#define GS 9       // L3 gate buffer stride

// ---- workspace float offsets ----
// L1/L2/L4: gate-interleaved [cell][k][4]; L3: [col][k]; FF: [col][k] padded.
#define L1W   0
#define L1B   18432
#define L2W   18624
#define L2B   92352
#define L3W   92736
#define L3B   258624
#define L4W   259200
#define L4B   277632
#define F1AW  277824
#define F1AB  278208
#define F1BW  278256
#define F1BB  280560
#define F2AW  280608
#define F2AB  301344
#define F2BW  301488
#define F2BB  315312
#define F3AW  315408
#define F3AB  324624
#define F3BW  324720
#define F3BB  329328
// total 329376 floats = 1.32 MB

// ---- pool float offsets ----
#define P_GB   0     // L3 gate buffer 576*9 = 5184 (live P4->P5)
#define P_F2H  0     // 144*12 = 1728 (live P6->P7, overlaps GB)
#define P_O4T  1728  // 96*12 = 1152 (P7->P8)
#define P_F3H  2880  // 96*12 = 1152 (P8->P9)
#define P_OUT5 4032  // 48*12 = 576 (P9->P10), ends 4608 < 5184
#define P_SAT  5184  // 8*12 = 96 (staged P10(t-1) -> read P2)
#define P_F1H  5280  // 48*12 = 576 (P2->P3)
#define POOLSZ 5856

#define H1SZ (48 * XS)
#define H2SZ (96 * XS)
#define H4SZ (48 * XS)

__device__ __forceinline__ float sigf(float x) { return 1.0f / (1.0f + __expf(-x)); }

// ---------------------------------------------------------------------------
// Prep kernels
// ---------------------------------------------------------------------------
// Gate-interleaved: W[(j*K + k)*4 + g] = concat(wih,whh)[g*H + j][k]
__global__ void prep_lstm_f(const float* __restrict__ wih, const float* __restrict__ whh,
                            const float* __restrict__ bih, const float* __restrict__ bhh,
                            float* __restrict__ W, float* __restrict__ bias,
                            int Din, int H) {
    int K = Din + H;
    int total = H * K * 4;
    for (int idx = blockIdx.x * blockDim.x + threadIdx.x; idx < total + 4 * H;
         idx += gridDim.x * blockDim.x) {
        if (idx < total) {
            int g = idx & 3;
            int kj = idx >> 2;
            int k = kj % K;
            int j = kj / K;
            int row = g * H + j;
            W[idx] = (k < Din) ? wih[row * Din + k] : whh[row * H + (k - Din)];
        } else {
            int i = idx - total;  // j*4+g
            int g = i & 3, j = i >> 2;
            bias[i] = bih[g * H + j] + bhh[g * H + j];
        }
    }
}

// Plain column-major (L3): W[c*K + k]
__global__ void prep_lstm(const float* __restrict__ wih, const float* __restrict__ whh,
                          const float* __restrict__ bih, const float* __restrict__ bhh,
                          float* __restrict__ W, float* __restrict__ bias,
                          int Din, int H) {
    int K = Din + H;
    int N = 4 * H;
    int total = N * K;
    for (int idx = blockIdx.x * blockDim.x + threadIdx.x; idx < total + N;
         idx += gridDim.x * blockDim.x) {
        if (idx < total) {
            int c = idx / K;
            int k = idx - c * K;
            W[idx] = (k < Din) ? wih[c * Din + k] : whh[c * H + (k - Din)];
        } else {
            int c = idx - total;
            bias[c] = bih[c] + bhh[c];
        }
    }
}

__global__ void prep_ff(const float* __restrict__ w, const float* __restrict__ b,
                        float* __restrict__ W, float* __restrict__ bias,
                        int K, int Kpad, int N) {
    int total = N * Kpad;
    for (int idx = blockIdx.x * blockDim.x + threadIdx.x; idx < total + N;
         idx += gridDim.x * blockDim.x) {
        if (idx < total) {
            int c = idx / Kpad;
            int k = idx - c * Kpad;
            W[idx] = (k < K) ? w[c * K + k] : 0.0f;
        } else {
            int c = idx - total;
            bias[c] = b[c];
        }
    }
}

// ---------------------------------------------------------------------------
// Fused LSTM cell-column: thread owns cell j, ROWS rows. Per k: one float4
// weight (4 gates) + one LDS read -> 4*ROWS FMAs. Epilogue in registers,
// h written to double-buffered hT (no barrier needed: readers use prev buf).
// ---------------------------------------------------------------------------
template <int ROWS, bool EMIT>
__device__ __forceinline__ void lstm_fused(
    const float* __restrict__ wp, float4 bv,
    const float* __restrict__ x0, int K0,
    const float* __restrict__ x1, int K1,
    const float* __restrict__ x2, int K2,
    int rbase, float* __restrict__ hdst,
    float (&cs)[ROWS], float* __restrict__ gout) {
    float ai[ROWS], af[ROWS], ag[ROWS], ao[ROWS];
#pragma unroll
    for (int r = 0; r < ROWS; ++r) { ai[r] = af[r] = ag[r] = ao[r] = 0.f; }
    int ko = 0;
#pragma unroll
    for (int s = 0; s < 3; ++s) {
        const float* xb = (s == 0) ? x0 : (s == 1) ? x1 : x2;
        int K = (s == 0) ? K0 : (s == 1) ? K1 : K2;
        if (K > 0) {
            const float* xp = xb + rbase;
            const float* wk = wp + (size_t)ko * 4;
#pragma unroll 4
            for (int k = 0; k < K; ++k) {
                float4 wv = *(const float4*)(wk + k * 4);
                if (ROWS == 2) {
                    float2 xv = *(const float2*)(xp + k * XS);
                    ai[0] = fmaf(xv.x, wv.x, ai[0]); ai[1] = fmaf(xv.y, wv.x, ai[1]);
                    af[0] = fmaf(xv.x, wv.y, af[0]); af[1] = fmaf(xv.y, wv.y, af[1]);
                    ag[0] = fmaf(xv.x, wv.z, ag[0]); ag[1] = fmaf(xv.y, wv.z, ag[1]);
                    ao[0] = fmaf(xv.x, wv.w, ao[0]); ao[1] = fmaf(xv.y, wv.w, ao[1]);
                } else {
                    float4 xv = *(const float4*)(xp + k * XS);
                    const float* xf = (const float*)&xv;
#pragma unroll
                    for (int r = 0; r < ROWS; ++r) {
                        ai[r] = fmaf(xf[r], wv.x, ai[r]);
                        af[r] = fmaf(xf[r], wv.y, af[r]);
                        ag[r] = fmaf(xf[r], wv.z, ag[r]);
                        ao[r] = fmaf(xf[r], wv.w, ao[r]);
                    }
                }
            }
            ko += K;
        }
    }
    float hv[ROWS];
#pragma unroll
    for (int r = 0; r < ROWS; ++r) {
        float gi = sigf(ai[r] + bv.x);
        float gf = sigf(af[r] + bv.y);
        float gg = tanhf(ag[r] + bv.z);
        float go = sigf(ao[r] + bv.w);
        float c2 = gf * cs[r] + gi * gg;
        cs[r] = c2;
        hv[r] = go * tanhf(c2);
    }
    if (ROWS == 2) {
        *(float2*)hdst = make_float2(hv[0], hv[1]);
    } else {
        *(float4*)hdst = make_float4(hv[0], hv[1], hv[2], hv[3]);
    }
    if (EMIT) {
#pragma unroll
        for (int r = 0; r < ROWS; ++r) gout[(size_t)r * 48] = hv[r];
    }
}

// ---------------------------------------------------------------------------
// FF column matmul: 1 col/thread, ROWS rows, single x segment, float4 x reads.
// ---------------------------------------------------------------------------
template <int ROWS>
__device__ __forceinline__ void ffmm(
    const float* __restrict__ w, float b,
    const float* __restrict__ x, int K,
    int rbase, float* __restrict__ dst) {
    float a[ROWS];
#pragma unroll
    for (int r = 0; r < ROWS; ++r) a[r] = 0.f;
    const float* xp = x + rbase;
#pragma unroll 2
    for (int k = 0; k < K; k += 4) {
        float4 wv = *(const float4*)(w + k);
        const float* wf = (const float*)&wv;
#pragma unroll
        for (int q = 0; q < 4; ++q) {
            const float* xq = xp + (k + q) * XS;
            if (ROWS == 8) {
                float4 u = *(const float4*)(xq);
                float4 v = *(const float4*)(xq + 4);
                a[0] = fmaf(u.x, wf[q], a[0]); a[1] = fmaf(u.y, wf[q], a[1]);
                a[2] = fmaf(u.z, wf[q], a[2]); a[3] = fmaf(u.w, wf[q], a[3]);
                a[4] = fmaf(v.x, wf[q], a[4]); a[5] = fmaf(v.y, wf[q], a[5]);
                a[6] = fmaf(v.z, wf[q], a[6]); a[7] = fmaf(v.w, wf[q], a[7]);
            } else if (ROWS == 4) {
                float4 u = *(const float4*)(xq);
                a[0] = fmaf(u.x, wf[q], a[0]); a[1] = fmaf(u.y, wf[q], a[1]);
                a[2] = fmaf(u.z, wf[q], a[2]); a[3] = fmaf(u.w, wf[q], a[3]);
            } else {
                float2 u = *(const float2*)(xq);
                a[0] = fmaf(u.x, wf[q], a[0]); a[1] = fmaf(u.y, wf[q], a[1]);
            }
        }
    }
#pragma unroll
    for (int r = 0; r < ROWS; ++r) a[r] = fmaxf(a[r] + b, 0.f);  // all FFs relu
    if (ROWS == 8) {
        *(float4*)(dst) = make_float4(a[0], a[1], a[2], a[3]);
        *(float4*)(dst + 4) = make_float4(a[4], a[5], a[6], a[7]);
    } else if (ROWS == 4) {
        *(float4*)(dst) = make_float4(a[0], a[1], a[2], a[3]);
    } else {
        *(float2*)(dst) = make_float2(a[0], a[1]);
    }
}

// ---------------------------------------------------------------------------
// L3 column matmul (unfused; gate groups span >256 threads): TC cols/thread,
// 8 rows, float4 x reads, gates to LDS buffer.
// ---------------------------------------------------------------------------
template <int TC>
__device__ __forceinline__ void l3mm(
    const float* __restrict__ w0, const float* __restrict__ w1,
    const float* __restrict__ w2,
    float b0, float b1, float b2,
    const float* __restrict__ x0, int K0,
    const float* __restrict__ x1, int K1,
    const float* __restrict__ x2, int K2,
    float* __restrict__ g0, float* __restrict__ g1, float* __restrict__ g2) {
    float a0[8], a1[8], a2[8];
#pragma unroll
    for (int r = 0; r < 8; ++r) { a0[r] = 0.f; a1[r] = 0.f; a2[r] = 0.f; }
    int ko = 0;
#pragma unroll
    for (int s = 0; s < 3; ++s) {
        const float* xb = (s == 0) ? x0 : (s == 1) ? x1 : x2;
        int K = (s == 0) ? K0 : (s == 1) ? K1 : K2;
        if (K > 0) {
#pragma unroll 2
            for (int k = 0; k < K; k += 4) {
                float4 wv0 = *(const float4*)(w0 + ko + k);
                float4 wv1 = *(const float4*)(w1 + ko + k);
                float4 wv2 = (TC > 2) ? *(const float4*)(w2 + ko + k) : wv0;
                const float* f0 = (const float*)&wv0;
                const float* f1p = (const float*)&wv1;
                const float* f2p = (const float*)&wv2;
#pragma unroll
                for (int q = 0; q < 4; ++q) {
                    const float* xq = xb + (k + q) * XS;
                    float4 u = *(const float4*)(xq);
                    float4 v = *(const float4*)(xq + 4);
                    const float* xf = (const float*)&u;
                    const float* yf = (const float*)&v;
#pragma unroll
                    for (int r = 0; r < 4; ++r) {
                        a0[r] = fmaf(xf[r], f0[q], a0[r]);
                        a0[r + 4] = fmaf(yf[r], f0[q], a0[r + 4]);
                        a1[r] = fmaf(xf[r], f1p[q], a1[r]);
                        a1[r + 4] = fmaf(yf[r], f1p[q], a1[r + 4]);
                        if (TC > 2) {
                            a2[r] = fmaf(xf[r], f2p[q], a2[r]);
                            a2[r + 4] = fmaf(yf[r], f2p[q], a2[r + 4]);
                        }
                    }
                }
            }
            ko += K;
        }
    }
#pragma unroll
    for (int r = 0; r < 8; ++r) {
        g0[r] = a0[r] + b0;
        g1[r] = a1[r] + b1;
        if (TC > 2) g2[r] = a2[r] + b2;
    }
}

// ---------------------------------------------------------------------------
// L3 epilogue + c-init (ownership idx = tid + n*NT)
// ---------------------------------------------------------------------------
template <int H, int R, int NCS>
__device__ __forceinline__ void lstm_epi(const float* __restrict__ gb, int gs,
                                         float* __restrict__ hT,
                                         float (&cs)[NCS], int idx0, int stride) {
    const int E = H * R;
#pragma unroll
    for (int n = 0; n < NCS; ++n) {
        int idx = idx0 + n * stride;
        if (idx < E) {
            int r = idx & (R - 1);
            int j = idx / R;
            float gi = gb[j * gs + r];
            float gf = gb[(j + H) * gs + r];
            float gg = gb[(j + 2 * H) * gs + r];
            float go = gb[(j + 3 * H) * gs + r];
            float c2 = sigf(gf) * cs[n] + sigf(gi) * tanhf(gg);
            cs[n] = c2;
            hT[j * XS + r] = sigf(go) * tanhf(c2);
        }
    }
}

template <int H, int R, int NCS>
__device__ __forceinline__ void c_init(const float* __restrict__ c0, int r0,
                                       float (&cs)[NCS], int idx0, int stride) {
    const int E = H * R;
#pragma unroll
    for (int n = 0; n < NCS; ++n) {
        int idx = idx0 + n * stride;
        if (idx < E) {
            int r = idx & (R - 1);
            int j = idx / R;
            cs[n] = c0[(size_t)(r0 + r) * H + j];
        }
    }
}

template <int ROWS>
__device__ __forceinline__ void c_init_f(const float* __restrict__ c0, int H,
                                         int r0, int rbase, int j, float (&cs)[ROWS]) {
#pragma unroll
    for (int i = 0; i < ROWS; ++i)
        cs[i] = c0[(size_t)(r0 + rbase + i) * H + j];
}

// ---------------------------------------------------------------------------
__global__ __launch_bounds__(256, 2) void model_kernel(
    const float* __restrict__ tactiles, const float* __restrict__ actions,
    const float* __restrict__ context, const float* __restrict__ ws,
    const float* __restrict__ h01, const float* __restrict__ c01,
    const float* __restrict__ h02, const float* __restrict__ c02,
    const float* __restrict__ h03, const float* __restrict__ c03,
    const float* __restrict__ h04, const float* __restrict__ c04,
    float* __restrict__ out) {
    __shared__ __align__(16) float tacT[48 * XS];
    __shared__ __align__(16) float ctxT[48 * XS];
    __shared__ __align__(16) float saoT[48 * XS];
    __shared__ __align__(16) float h1T[2 * H1SZ];
    __shared__ __align__(16) float h2T[2 * H2SZ];
    __shared__ __align__(16) float h3T[144 * XS];
    __shared__ __align__(16) float h4T[2 * H4SZ];
    __shared__ __align__(16) float pool[POOLSZ];

    const int tid = threadIdx.x;
    const int r0 = blockIdx.x * MROWS;

    // ---- init h states into PREV (=1) buffers; h3 single ----
    for (int i = tid; i < 48 * 8; i += NT) {
        int r = i & 7, j = i >> 3;
        h1T[H1SZ + j * XS + r] = h01[(size_t)(r0 + r) * 48 + j];
        h4T[H4SZ + j * XS + r] = h04[(size_t)(r0 + r) * 48 + j];
    }
    for (int i = tid; i < 96 * 8; i += NT) {
        int r = i & 7, j = i >> 3;
        h2T[H2SZ + j * XS + r] = h02[(size_t)(r0 + r) * 96 + j];
    }
    for (int i = tid; i < 144 * 8; i += NT) {
        int r = i & 7, j = i >> 3;
        h3T[j * XS + r] = h03[(size_t)(r0 + r) * 144 + j];
    }

    // ---- c states in registers (fused ownership = (cell j, row group)) ----
    float cs1[2] = {0.f, 0.f};
    float cs2[4] = {0.f, 0.f, 0.f, 0.f};
    float cs3[5] = {0.f, 0.f, 0.f, 0.f, 0.f};
    float cs4[2] = {0.f, 0.f};
    if (tid < 192) {
        c_init_f<2>(c01, 48, r0, (tid & 3) * 2, tid >> 2, cs1);
        c_init_f<4>(c02, 96, r0, (tid & 1) * 4, tid >> 1, cs2);
        c_init_f<2>(c04, 48, r0, (tid & 3) * 2, tid >> 2, cs4);
    }
    c_init<144, 8, 5>(c03, r0, cs3, tid, NT);

    // ---- hoist biases ----
    float4 bL1v = make_float4(0.f, 0.f, 0.f, 0.f), bL2v = bL1v, bL4v = bL1v;
    if (tid < 192) {
        bL1v = *(const float4*)(ws + L1B + (tid >> 2) * 4);
        bL2v = *(const float4*)(ws + L2B + (tid >> 1) * 4);
        bL4v = *(const float4*)(ws + L4B + (tid >> 2) * 4);
    }
    float bL3a = ws[L3B + tid];
    float bL3b = ws[L3B + tid + 256];
    float bL3c = (tid < 64) ? ws[L3B + tid + 512] : 0.f;
    float bF1a = (tid >= 192 && tid < 240) ? ws[F1AB + (tid - 192)] : 0.f;
    float bF1b = (tid >= 192 && tid < 240) ? ws[F1BB + (tid - 192)] : 0.f;
    float bF2a = (tid < 144) ? ws[F2AB + tid] : 0.f;
    float bF2b = (tid < 192) ? ws[F2BB + (tid % 96)] : 0.f;
    float bF3a = (tid < 192) ? ws[F3AB + (tid % 96)] : 0.f;
    float bF3b = (tid < 192) ? ws[F3BB + (tid % 48)] : 0.f;

    const int wvid = tid >> 6;

    // ---- pre-loop stage for t=0 ----
    {
        const float* src = tactiles + (size_t)r0 * 48;
        for (int i = tid; i < 96; i += NT) {
            int r = i / 12, k4 = (i % 12) * 4;
            float4 v = *(const float4*)(src + r * 48 + k4);
            tacT[(k4 + 0) * XS + r] = v.x;
            tacT[(k4 + 1) * XS + r] = v.y;
            tacT[(k4 + 2) * XS + r] = v.z;
            tacT[(k4 + 3) * XS + r] = v.w;
        }
        const float* csrc = context + (size_t)r0 * 48;
        for (int i = tid; i < 96; i += NT) {
            int r = i / 12, k4 = (i % 12) * 4;
            float4 v = *(const float4*)(csrc + r * 48 + k4);
            ctxT[(k4 + 0) * XS + r] = v.x;
            ctxT[(k4 + 1) * XS + r] = v.y;
            ctxT[(k4 + 2) * XS + r] = v.z;
            ctxT[(k4 + 3) * XS + r] = v.w;
        }
        if (tid < 64) {
            int r = tid & 7, k = tid >> 3;
            float v = 0.f;
            if (k < 3) v = actions[(size_t)(r0 + r) * 3 + k];
            else if (k < 6) v = actions[(size_t)(r0 + r) * 3 + (k - 3)];
            pool[P_SAT + k * XS + r] = v;
        }
    }
    __syncthreads();

    for (int t = 0; t < TSTEPS; ++t) {
        const int cur = t & 1, prev = cur ^ 1;

        // ---- P2: L1 fused (0-191) || f1a (192-239) ----
        if (tid < 192) {
            int j = tid >> 2, rg = tid & 3;
            const float* x1src = (t < 6) ? tacT : (h4T + prev * H4SZ);
            lstm_fused<2, false>(ws + L1W + (size_t)j * 96 * 4, bL1v,
                                 x1src, 48, h1T + prev * H1SZ, 48, nullptr, 0,
                                 rg * 2, h1T + cur * H1SZ + j * XS + rg * 2,
                                 cs1, nullptr);
        } else if (tid < 240) {
            ffmm<8>(ws + F1AW + (tid - 192) * 8, bF1a, pool + P_SAT, 8, 0,
                    pool + P_F1H + (tid - 192) * XS);
        }
        __syncthreads();

        // ---- P3: L2 fused (0-191) || f1b (192-239) ----
        if (tid < 192) {
            int j = tid >> 1, rg = tid & 1;
            lstm_fused<4, false>(ws + L2W + (size_t)j * 192 * 4, bL2v,
                                 ctxT, 48, h1T + cur * H1SZ, 48, h2T + prev * H2SZ, 96,
                                 rg * 4, h2T + cur * H2SZ + j * XS + rg * 4,
                                 cs2, nullptr);
        } else if (tid < 240) {
            ffmm<8>(ws + F1BW + (tid - 192) * 48, bF1b, pool + P_F1H, 48, 0,
                    saoT + (tid - 192) * XS);
        }
        __syncthreads();

        // ---- P4: L3 mm (all 256) ----
        if (wvid == 0)
            l3mm<3>(ws + L3W + (size_t)tid * 288, ws + L3W + (size_t)(tid + 256) * 288,
                    ws + L3W + (size_t)(tid + 512) * 288, bL3a, bL3b, bL3c,
                    saoT, 48, h2T + cur * H2SZ, 96, h3T, 144,
                    pool + P_GB + tid * GS, pool + P_GB + (tid + 256) * GS,
                    pool + P_GB + (tid + 512) * GS);
        else
            l3mm<2>(ws + L3W + (size_t)tid * 288, ws + L3W + (size_t)(tid + 256) * 288,
                    ws, bL3a, bL3b, 0.f,
                    saoT, 48, h2T + cur * H2SZ, 96, h3T, 144,
                    pool + P_GB + tid * GS, pool + P_GB + (tid + 256) * GS, nullptr);
        __syncthreads();
        // ---- P5: L3 epilogue ----
        lstm_epi<144, 8, 5>(pool + P_GB, GS, h3T, cs3, tid, NT);
        __syncthreads();

        // ---- P6: f2a 144->144 ----
        if (tid < 144)
            ffmm<8>(ws + F2AW + tid * 144, bF2a, h3T, 144, 0,
                    pool + P_F2H + tid * XS);
        __syncthreads();
        // ---- P7: f2b 144->96 (4-row halves) ----
        if (tid < 192) {
            int c = tid % 96, rb = (tid / 96) * 4;
            ffmm<4>(ws + F2BW + c * 144, bF2b, pool + P_F2H, 144, rb,
                    pool + P_O4T + c * XS + rb);
        }
        __syncthreads();
        // ---- P8: f3a 96->96 (4-row halves) ----
        if (tid < 192) {
            int c = tid % 96, rb = (tid / 96) * 4;
            ffmm<4>(ws + F3AW + c * 96, bF3a, pool + P_O4T, 96, rb,
                    pool + P_F3H + c * XS + rb);
        }
        __syncthreads();
        // ---- P9: f3b 96->48 (2-row quarters) ----
        if (tid < 192) {
            int c = tid % 48, rb = (tid / 48) * 2;
            ffmm<2>(ws + F3BW + c * 96, bF3b, pool + P_F3H, 96, rb,
                    pool + P_OUT5 + c * XS + rb);
        }
        __syncthreads();

        // ---- P10: L4 fused + emit (0-191) || stage t+1 (192-255) ----
        if (tid < 192) {
            int j = tid >> 2, rg = tid & 3;
            float* gout = out + (size_t)t * (BATCH * 48) + (size_t)(r0 + rg * 2) * 48 + j;
            lstm_fused<2, true>(ws + L4W + (size_t)j * 96 * 4, bL4v,
                                pool + P_OUT5, 48, h4T + prev * H4SZ, 48, nullptr, 0,
                                rg * 2, h4T + cur * H4SZ + j * XS + rg * 2,
                                cs4, gout);
        } else if (t + 1 < TSTEPS) {
            int i2 = tid - 192;
            if (t + 1 < 6) {
                const float* src = tactiles + (size_t)(t + 1) * (BATCH * 48) + (size_t)r0 * 48;
                for (int i = i2; i < 96; i += 64) {
                    int r = i / 12, k4 = (i % 12) * 4;
                    float4 v = *(const float4*)(src + r * 48 + k4);
                    tacT[(k4 + 0) * XS + r] = v.x;
                    tacT[(k4 + 1) * XS + r] = v.y;
                    tacT[(k4 + 2) * XS + r] = v.z;
                    tacT[(k4 + 3) * XS + r] = v.w;
                }
            }
            {
                const float* src = context + (size_t)(t + 1) * (BATCH * 48) + (size_t)r0 * 48;
                for (int i = i2; i < 96; i += 64) {
                    int r = i / 12, k4 = (i % 12) * 4;
                    float4 v = *(const float4*)(src + r * 48 + k4);
                    ctxT[(k4 + 0) * XS + r] = v.x;
                    ctxT[(k4 + 1) * XS + r] = v.y;
                    ctxT[(k4 + 2) * XS + r] = v.z;
                    ctxT[(k4 + 3) * XS + r] = v.w;
                }
            }
            {
                int r = i2 & 7, k = i2 >> 3;
                float v = 0.f;
                if (k < 3) v = actions[(size_t)(r0 + r) * 3 + k];
                else if (k < 6) v = actions[(size_t)(t + 1) * (BATCH * 3) + (size_t)(r0 + r) * 3 + (k - 3)];
                pool[P_SAT + k * XS + r] = v;
            }
        }
        __syncthreads();
    }
}

// ---------------------------------------------------------------------------
extern "C" void kernel_launch(void* const* d_in, const int* in_sizes, int n_in,
                              void* d_out, int out_size, void* d_ws, size_t ws_size,
                              hipStream_t stream) {
    const float* tac = (const float*)d_in[0];
    const float* act = (const float*)d_in[1];
    const float* ctx = (const float*)d_in[2];

    const float* l1_wih = (const float*)d_in[3];
    const float* l1_whh = (const float*)d_in[4];
    const float* l1_bih = (const float*)d_in[5];
    const float* l1_bhh = (const float*)d_in[6];
    const float* l2_wih = (const float*)d_in[7];
    const float* l2_whh = (const float*)d_in[8];
    const float* l2_bih = (const float*)d_in[9];
    const float* l2_bhh = (const float*)d_in[10];
    const float* l3_wih = (const float*)d_in[11];
    const float* l3_whh = (const float*)d_in[12];
    const float* l3_bih = (const float*)d_in[13];
    const float* l3_bhh = (const float*)d_in[14];
    const float* l4_wih = (const float*)d_in[15];
    const float* l4_whh = (const float*)d_in[16];
    const float* l4_bih = (const float*)d_in[17];
    const float* l4_bhh = (const float*)d_in[18];

    const float* f1_w1 = (const float*)d_in[19];
    const float* f1_b1 = (const float*)d_in[20];
    const float* f1_w2 = (const float*)d_in[21];
    const float* f1_b2 = (const float*)d_in[22];
    const float* f2_w1 = (const float*)d_in[23];
    const float* f2_b1 = (const float*)d_in[24];
    const float* f2_w2 = (const float*)d_in[25];
    const float* f2_b2 = (const float*)d_in[26];
    const float* f3_w1 = (const float*)d_in[27];
    const float* f3_b1 = (const float*)d_in[28];
    const float* f3_w2 = (const float*)d_in[29];
    const float* f3_b2 = (const float*)d_in[30];

    const float* h01 = (const float*)d_in[31];
    const float* c01 = (const float*)d_in[32];
    const float* h02 = (const float*)d_in[33];
    const float* c02 = (const float*)d_in[34];
    const float* h03 = (const float*)d_in[35];
    const float* c03 = (const float*)d_in[36];
    const float* h04 = (const float*)d_in[37];
    const float* c04 = (const float*)d_in[38];

    float* ws = (float*)d_ws;
    float* out = (float*)d_out;

    dim3 blk(NT);
    hipLaunchKernelGGL(prep_lstm_f, dim3(96), blk, 0, stream,
                       l1_wih, l1_whh, l1_bih, l1_bhh, ws + L1W, ws + L1B, 48, 48);
    hipLaunchKernelGGL(prep_lstm_f, dim3(256), blk, 0, stream,
                       l2_wih, l2_whh, l2_bih, l2_bhh, ws + L2W, ws + L2B, 96, 96);
    hipLaunchKernelGGL(prep_lstm, dim3(256), blk, 0, stream,
                       l3_wih, l3_whh, l3_bih, l3_bhh, ws + L3W, ws + L3B, 144, 144);
    hipLaunchKernelGGL(prep_lstm_f, dim3(96), blk, 0, stream,
                       l4_wih, l4_whh, l4_bih, l4_bhh, ws + L4W, ws + L4B, 48, 48);

    hipLaunchKernelGGL(prep_ff, dim3(4), blk, 0, stream,
                       f1_w1, f1_b1, ws + F1AW, ws + F1AB, 6, 8, 48);
    hipLaunchKernelGGL(prep_ff, dim3(16), blk, 0, stream,
                       f1_w2, f1_b2, ws + F1BW, ws + F1BB, 48, 48, 48);
    hipLaunchKernelGGL(prep_ff, dim3(96), blk, 0, stream,
                       f2_w1, f2_b1, ws + F2AW, ws + F2AB, 144, 144, 144);
    hipLaunchKernelGGL(prep_ff, dim3(64), blk, 0, stream,
                       f2_w2, f2_b2, ws + F2BW, ws + F2BB, 144, 144, 96);
    hipLaunchKernelGGL(prep_ff, dim3(48), blk, 0, stream,
                       f3_w1, f3_b1, ws + F3AW, ws + F3AB, 96, 96, 96);
    hipLaunchKernelGGL(prep_ff, dim3(24), blk, 0, stream,
                       f3_w2, f3_b2, ws + F3BW, ws + F3BB, 96, 96, 48);

    hipLaunchKernelGGL(model_kernel, dim3(BATCH / MROWS), blk, 0, stream,
                       tac, act, ctx, ws,
                       h01, c01, h02, c02, h03, c03, h04, c04, out);
}